// Round 1
// baseline (378.627 us; speedup 1.0000x reference)
//
#include <hip/hip_runtime.h>
#include <hip/hip_bf16.h>

// Attention_4363686773373: sigmoid attention block, all-bf16 MFMA pipeline.
// B=4 T=2048 D=768 H=12 HD=64.  Output fp32.

typedef __bf16 bf16_t;
typedef __bf16 bf16x8 __attribute__((ext_vector_type(8)));
typedef float floatx4 __attribute__((ext_vector_type(4)));

#define MFMA16x16x32(a, b, c) __builtin_amdgcn_mfma_f32_16x16x32_bf16((a), (b), (c), 0, 0, 0)

static constexpr float kEPS  = 1e-4f;
static constexpr float kGAIN = 1.8402f;

// ---------------------------------------------------------------------------
// 1) row-normalize a (nrows x ncols) fp32 weight matrix -> bf16: w/(||w||+eps)
// ---------------------------------------------------------------------------
__global__ __launch_bounds__(256) void rownorm_kernel(const float* __restrict__ w,
                                                      bf16_t* __restrict__ wn,
                                                      int ncols) {
    int row = blockIdx.x;
    const float* wr = w + (size_t)row * ncols;
    float ss = 0.f;
    for (int c = threadIdx.x; c < ncols; c += 256) { float v = wr[c]; ss += v * v; }
    for (int m = 32; m; m >>= 1) ss += __shfl_xor(ss, m, 64);
    __shared__ float red[4];
    if ((threadIdx.x & 63) == 0) red[threadIdx.x >> 6] = ss;
    __syncthreads();
    float inv = 1.0f / (sqrtf(red[0] + red[1] + red[2] + red[3]) + kEPS);
    bf16_t* wo = wn + (size_t)row * ncols;
    for (int c = threadIdx.x; c < ncols; c += 256) wo[c] = (bf16_t)(wr[c] * inv);
}

// ---------------------------------------------------------------------------
// 2) x -> bf16 copy + per-token magnitude ||x||/sqrt(D)
// ---------------------------------------------------------------------------
__global__ __launch_bounds__(256) void prep_x_kernel(const float* __restrict__ x,
                                                     bf16_t* __restrict__ xb,
                                                     float* __restrict__ mag) {
    int tok = blockIdx.x;                 // 0..8191
    const float* xr = x + (size_t)tok * 768;
    float ss = 0.f;
    for (int c = threadIdx.x; c < 768; c += 256) { float v = xr[c]; ss += v * v; }
    for (int m = 32; m; m >>= 1) ss += __shfl_xor(ss, m, 64);
    __shared__ float red[4];
    if ((threadIdx.x & 63) == 0) red[threadIdx.x >> 6] = ss;
    __syncthreads();
    float tot = red[0] + red[1] + red[2] + red[3];
    if (threadIdx.x == 0) mag[tok] = sqrtf(tot) * 0.036084391824352f;  // 1/sqrt(768)
    bf16_t* xo = xb + (size_t)tok * 768;
    for (int c = threadIdx.x; c < 768; c += 256) xo[c] = (bf16_t)xr[c];
}

// ---------------------------------------------------------------------------
// 3) GEMM1: qkv = xb(8192x768) @ wn^T(2304x768) -> bf16 in (p,b,h,t,d) layout
//    tile 128x128, BK=32, 4 waves in 2x2; m89-verified fragment layouts.
// ---------------------------------------------------------------------------
__global__ __launch_bounds__(256) void gemm_qkv_kernel(const bf16_t* __restrict__ A,
                                                       const bf16_t* __restrict__ Bw,
                                                       bf16_t* __restrict__ qkvh) {
    __shared__ bf16_t As[128][40];   // +8 pad: 80B rows -> 2-way banks (free)
    __shared__ bf16_t Bs[128][40];
    const int m0 = blockIdx.x * 128;
    const int n0 = blockIdx.y * 128;
    const int tid = threadIdx.x;
    const int wave = tid >> 6, lane = tid & 63;
    const int quad = lane >> 4, l16 = lane & 15;
    const int wr = (wave >> 1) * 64, wc = (wave & 1) * 64;

    floatx4 acc[4][4];
    for (int i = 0; i < 4; i++)
        for (int j = 0; j < 4; j++) acc[i][j] = (floatx4){0.f, 0.f, 0.f, 0.f};

    for (int k0 = 0; k0 < 768; k0 += 32) {
        for (int s = tid; s < 512; s += 256) {
            int r = s >> 2, cs = (s & 3) * 8;
            *(uint4*)&As[r][cs] = *(const uint4*)&A[(size_t)(m0 + r) * 768 + k0 + cs];
            *(uint4*)&Bs[r][cs] = *(const uint4*)&Bw[(size_t)(n0 + r) * 768 + k0 + cs];
        }
        __syncthreads();
        bf16x8 af[4], bfr[4];
        for (int i = 0; i < 4; i++) af[i]  = *(const bf16x8*)&As[wr + i * 16 + l16][quad * 8];
        for (int j = 0; j < 4; j++) bfr[j] = *(const bf16x8*)&Bs[wc + j * 16 + l16][quad * 8];
        for (int i = 0; i < 4; i++)
            for (int j = 0; j < 4; j++) acc[i][j] = MFMA16x16x32(af[i], bfr[j], acc[i][j]);
        __syncthreads();
    }
    // epilogue: C[m][n] -> qkvh[(((p*4+b)*12+h)*2048+t)*64+d], bf16
    for (int i = 0; i < 4; i++)
        for (int j = 0; j < 4; j++) {
            int n = n0 + wc + j * 16 + l16;
            int p = n / 768, rem = n - p * 768;
            int h = rem >> 6, d = rem & 63;
            for (int r = 0; r < 4; r++) {
                int m = m0 + wr + i * 16 + quad * 4 + r;
                int bat = m >> 11, t = m & 2047;
                qkvh[((((size_t)p * 4 + bat) * 12 + h) * 2048 + t) * 64 + d] =
                    (bf16_t)acc[i][j][r];
            }
        }
}

// ---------------------------------------------------------------------------
// 4) normalize q,k 64-segments in place: v * 8/(||v||+eps). One wave per seg.
//    segments 0 .. 2*4*12*2048-1 cover exactly the q and k parts of qkvh.
// ---------------------------------------------------------------------------
__global__ __launch_bounds__(256) void qknorm_kernel(bf16_t* __restrict__ qkvh) {
    int seg = blockIdx.x * 4 + (threadIdx.x >> 6);
    int lane = threadIdx.x & 63;
    bf16_t* p = qkvh + (size_t)seg * 64;
    float v = (float)p[lane];
    float ss = v * v;
    for (int m = 32; m; m >>= 1) ss += __shfl_xor(ss, m, 64);
    p[lane] = (bf16_t)(v * (8.0f / (sqrtf(ss) + kEPS)));
}

// ---------------------------------------------------------------------------
// 5) transpose v part (p=2) to vT[(b*12+h)*64 + d][t]  (64 x 2048 per head)
// ---------------------------------------------------------------------------
__global__ __launch_bounds__(256) void transpose_v_kernel(const bf16_t* __restrict__ qkvh,
                                                          bf16_t* __restrict__ vT) {
    int bh = blockIdx.x;           // 0..47
    int t0 = blockIdx.y * 64;      // 32 tiles
    __shared__ bf16_t tile[64][65];
    const bf16_t* src = qkvh + (((size_t)(2 * 4 * 12) + bh) * 2048 + t0) * 64;
    for (int s = threadIdx.x; s < 512; s += 256) {
        int r = s >> 3, cs = (s & 7) * 8;
        bf16_t tmp[8];
        *(uint4*)tmp = *(const uint4*)&src[(size_t)r * 64 + cs];
        for (int j = 0; j < 8; j++) tile[r][cs + j] = tmp[j];
    }
    __syncthreads();
    bf16_t* dst = vT + ((size_t)bh * 64) * 2048 + t0;
    for (int s = threadIdx.x; s < 512; s += 256) {
        int d = s >> 3, ts = (s & 7) * 8;
        bf16_t tmp[8];
        for (int j = 0; j < 8; j++) tmp[j] = tile[ts + j][d];
        *(uint4*)&dst[(size_t)d * 2048 + ts] = *(uint4*)tmp;
    }
}

// ---------------------------------------------------------------------------
// 6) sigmoid attention, fused per-head output normalize + mag rescale.
//    grid (T/128, 48). Q-tile 128 rows, s-tile 64. No softmax state needed.
// ---------------------------------------------------------------------------
__global__ __launch_bounds__(256) void attn_kernel(const bf16_t* __restrict__ qkvh,
                                                   const bf16_t* __restrict__ vT,
                                                   const float* __restrict__ mag,
                                                   bf16_t* __restrict__ y) {
    __shared__ bf16_t Qs[128][72];   // 72 = 64+8 pad (16B-aligned rows, 2-way banks)
    __shared__ bf16_t Ks[64][72];
    __shared__ bf16_t Vt[64][72];    // Vt[d][s_local]
    __shared__ bf16_t Ps[128][72];   // P[m][s_local], wave-private rows

    const int bh = blockIdx.y, bat = bh / 12, h = bh % 12;
    const int m0 = blockIdx.x * 128;
    const bf16_t* qbase = qkvh + (((size_t)bat * 12 + h) * 2048) * 64;            // p=0
    const bf16_t* kbase = qkvh + (((size_t)(4 + bat) * 12 + h) * 2048) * 64;      // p=1
    const bf16_t* vbase = vT + ((size_t)bh * 64) * 2048;

    const int tid = threadIdx.x, wave = tid >> 6, lane = tid & 63;
    const int quad = lane >> 4, l16 = lane & 15;

    for (int s = tid; s < 1024; s += 256) {   // 128 rows x 8 segs
        int r = s >> 3, cs = (s & 7) * 8;
        *(uint4*)&Qs[r][cs] = *(const uint4*)&qbase[(size_t)(m0 + r) * 64 + cs];
    }

    floatx4 o[2][4];
    for (int i = 0; i < 2; i++)
        for (int j = 0; j < 4; j++) o[i][j] = (floatx4){0.f, 0.f, 0.f, 0.f};

    for (int s0 = 0; s0 < 2048; s0 += 64) {
        __syncthreads();   // Qs visible (iter 0); prev-iter Ks/Vt reads done
        for (int s = tid; s < 512; s += 256) {
            int r = s >> 3, cs = (s & 7) * 8;
            *(uint4*)&Ks[r][cs] = *(const uint4*)&kbase[(size_t)(s0 + r) * 64 + cs];
            *(uint4*)&Vt[r][cs] = *(const uint4*)&vbase[(size_t)r * 2048 + s0 + cs];
        }
        __syncthreads();

        // S = Q.K^T for this wave's 32 rows x 64 s-cols (K-dim 64 = 2 mfma)
        floatx4 sacc[2][4];
        for (int i = 0; i < 2; i++)
            for (int j = 0; j < 4; j++) sacc[i][j] = (floatx4){0.f, 0.f, 0.f, 0.f};
        for (int i = 0; i < 2; i++) {
            bf16x8 a0 = *(const bf16x8*)&Qs[wave * 32 + i * 16 + l16][quad * 8];
            bf16x8 a1 = *(const bf16x8*)&Qs[wave * 32 + i * 16 + l16][32 + quad * 8];
            for (int j = 0; j < 4; j++) {
                bf16x8 b0 = *(const bf16x8*)&Ks[j * 16 + l16][quad * 8];
                bf16x8 b1 = *(const bf16x8*)&Ks[j * 16 + l16][32 + quad * 8];
                sacc[i][j] = MFMA16x16x32(a0, b0, sacc[i][j]);
                sacc[i][j] = MFMA16x16x32(a1, b1, sacc[i][j]);
            }
        }
        // sigmoid(S/8) -> Ps (wave-private rows: no barrier needed, lgkmcnt only)
        for (int i = 0; i < 2; i++)
            for (int j = 0; j < 4; j++)
                for (int r = 0; r < 4; r++) {
                    float v = sacc[i][j][r] * 0.125f;
                    float pv = 1.0f / (1.0f + __expf(-v));
                    Ps[wave * 32 + i * 16 + quad * 4 + r][j * 16 + l16] = (bf16_t)pv;
                }
        // O += P(32x64) . V(64x64); B-frag reads Vt[d][s] contiguous
        for (int i = 0; i < 2; i++) {
            bf16x8 a0 = *(const bf16x8*)&Ps[wave * 32 + i * 16 + l16][quad * 8];
            bf16x8 a1 = *(const bf16x8*)&Ps[wave * 32 + i * 16 + l16][32 + quad * 8];
            for (int j = 0; j < 4; j++) {
                bf16x8 b0 = *(const bf16x8*)&Vt[j * 16 + l16][quad * 8];
                bf16x8 b1 = *(const bf16x8*)&Vt[j * 16 + l16][32 + quad * 8];
                o[i][j] = MFMA16x16x32(a0, b0, o[i][j]);
                o[i][j] = MFMA16x16x32(a1, b1, o[i][j]);
            }
        }
    }

    // epilogue: out = mag * 8 * (kGAIN/sqrt(T)) * o / (||kGAIN/sqrt(T)*o|| + eps)
    const float kfac = kGAIN * 0.02209708691207961f;  // 1.8402/sqrt(2048)
    for (int i = 0; i < 2; i++)
        for (int r = 0; r < 4; r++) {
            int t = m0 + wave * 32 + i * 16 + quad * 4 + r;
            float vals[4];
            float ss = 0.f;
            for (int j = 0; j < 4; j++) {
                float v = o[i][j][r] * kfac;
                vals[j] = v;
                ss += v * v;
            }
            // row lives in one quad: reduce over 16 lanes (4 cols each)
            for (int msk = 1; msk < 16; msk <<= 1) ss += __shfl_xor(ss, msk, 64);
            float mg = mag[bat * 2048 + t];
            float sc = mg * 8.0f / (sqrtf(ss) + kEPS);
            for (int j = 0; j < 4; j++) {
                int d = j * 16 + l16;
                y[((size_t)(bat * 2048 + t)) * 768 + h * 64 + d] = (bf16_t)(vals[j] * sc);
            }
        }
}

// ---------------------------------------------------------------------------
// 7) GEMM2: out = y(8192x768) @ ow^T(768x768) -> fp32 d_out
// ---------------------------------------------------------------------------
__global__ __launch_bounds__(256) void gemm_out_kernel(const bf16_t* __restrict__ A,
                                                       const bf16_t* __restrict__ Bw,
                                                       float* __restrict__ out) {
    __shared__ bf16_t As[128][40];
    __shared__ bf16_t Bs[128][40];
    const int m0 = blockIdx.x * 128;
    const int n0 = blockIdx.y * 128;
    const int tid = threadIdx.x;
    const int wave = tid >> 6, lane = tid & 63;
    const int quad = lane >> 4, l16 = lane & 15;
    const int wr = (wave >> 1) * 64, wc = (wave & 1) * 64;

    floatx4 acc[4][4];
    for (int i = 0; i < 4; i++)
        for (int j = 0; j < 4; j++) acc[i][j] = (floatx4){0.f, 0.f, 0.f, 0.f};

    for (int k0 = 0; k0 < 768; k0 += 32) {
        for (int s = tid; s < 512; s += 256) {
            int r = s >> 2, cs = (s & 3) * 8;
            *(uint4*)&As[r][cs] = *(const uint4*)&A[(size_t)(m0 + r) * 768 + k0 + cs];
            *(uint4*)&Bs[r][cs] = *(const uint4*)&Bw[(size_t)(n0 + r) * 768 + k0 + cs];
        }
        __syncthreads();
        bf16x8 af[4], bfr[4];
        for (int i = 0; i < 4; i++) af[i]  = *(const bf16x8*)&As[wr + i * 16 + l16][quad * 8];
        for (int j = 0; j < 4; j++) bfr[j] = *(const bf16x8*)&Bs[wc + j * 16 + l16][quad * 8];
        for (int i = 0; i < 4; i++)
            for (int j = 0; j < 4; j++) acc[i][j] = MFMA16x16x32(af[i], bfr[j], acc[i][j]);
        __syncthreads();
    }
    for (int i = 0; i < 4; i++)
        for (int j = 0; j < 4; j++) {
            int n = n0 + wc + j * 16 + l16;
            for (int r = 0; r < 4; r++) {
                int m = m0 + wr + i * 16 + quad * 4 + r;
                out[(size_t)m * 768 + n] = acc[i][j][r];
            }
        }
}

// ---------------------------------------------------------------------------
extern "C" void kernel_launch(void* const* d_in, const int* in_sizes, int n_in,
                              void* d_out, int out_size, void* d_ws, size_t ws_size,
                              hipStream_t stream) {
    const float* x     = (const float*)d_in[0];   // (4,2048,768)
    const float* qkv_w = (const float*)d_in[1];   // (2304,768)
    const float* out_w = (const float*)d_in[2];   // (768,768)
    float* out = (float*)d_out;

    char* ws = (char*)d_ws;
    // workspace layout (bytes), all 256-aligned; y aliases xb (xb dead by then)
    bf16_t* wn   = (bf16_t*)(ws + 0);            //  3,538,944  (2304x768 bf16)
    bf16_t* ow   = (bf16_t*)(ws + 3538944);      //  1,179,648  (768x768 bf16)
    bf16_t* xb   = (bf16_t*)(ws + 4718592);      // 12,582,912  (8192x768 bf16)
    float*  mag  = (float*) (ws + 17301504);     //     32,768  (8192 fp32)
    bf16_t* qkvh = (bf16_t*)(ws + 17334272);     // 37,748,736  (3x4x12x2048x64 bf16)
    bf16_t* vT   = (bf16_t*)(ws + 55083008);     // 12,582,912  (48x64x2048 bf16)
    bf16_t* y    = (bf16_t*)(ws + 67665920);     // 12,582,912  (8192x768 bf16)
    // total 80,248,832 bytes

    rownorm_kernel<<<2304, 256, 0, stream>>>(qkv_w, wn, 768);
    rownorm_kernel<<<768, 256, 0, stream>>>(out_w, ow, 768);
    prep_x_kernel<<<8192, 256, 0, stream>>>(x, xb, mag);
    gemm_qkv_kernel<<<dim3(64, 18), 256, 0, stream>>>(xb, wn, qkvh);
    qknorm_kernel<<<49152, 256, 0, stream>>>(qkvh);
    transpose_v_kernel<<<dim3(48, 32), 256, 0, stream>>>(qkvh, vT);
    attn_kernel<<<dim3(16, 48), 256, 0, stream>>>(qkvh, vT, mag, y);
    gemm_out_kernel<<<dim3(64, 6), 256, 0, stream>>>(y, ow, out);
}

// Round 2
// 253.323 us; speedup vs baseline: 1.4946x; 1.4946x over previous
//
#include <hip/hip_runtime.h>
#include <hip/hip_bf16.h>

// Attention_4363686773373: sigmoid attention block, all-bf16 MFMA pipeline.
// B=4 T=2048 D=768 H=12 HD=64.  Output fp32.
// R2: attn rework — swizzled LDS (48KB, 3 blocks/CU), Q-frags in regs,
// QP LDS reuse for Ps, single-barrier dbuf K/V pipeline, pi-packed Ps b64
// writes, exp2/rcp sigmoid; qknorm fused into gemm_qkv epilogue.

typedef __bf16 bf16_t;
typedef __bf16 bf16x8 __attribute__((ext_vector_type(8)));
typedef __bf16 bf16x4 __attribute__((ext_vector_type(4)));
typedef float floatx4 __attribute__((ext_vector_type(4)));

#define MFMA16x16x32(a, b, c) __builtin_amdgcn_mfma_f32_16x16x32_bf16((a), (b), (c), 0, 0, 0)

static constexpr float kEPS  = 1e-4f;
static constexpr float kGAIN = 1.8402f;

// ---------------------------------------------------------------------------
// 1) row-normalize a (nrows x ncols) fp32 weight matrix -> bf16: w/(||w||+eps)
// ---------------------------------------------------------------------------
__global__ __launch_bounds__(256) void rownorm_kernel(const float* __restrict__ w,
                                                      bf16_t* __restrict__ wn,
                                                      int ncols) {
    int row = blockIdx.x;
    const float* wr = w + (size_t)row * ncols;
    float ss = 0.f;
    for (int c = threadIdx.x; c < ncols; c += 256) { float v = wr[c]; ss += v * v; }
    for (int m = 32; m; m >>= 1) ss += __shfl_xor(ss, m, 64);
    __shared__ float red[4];
    if ((threadIdx.x & 63) == 0) red[threadIdx.x >> 6] = ss;
    __syncthreads();
    float inv = 1.0f / (sqrtf(red[0] + red[1] + red[2] + red[3]) + kEPS);
    bf16_t* wo = wn + (size_t)row * ncols;
    for (int c = threadIdx.x; c < ncols; c += 256) wo[c] = (bf16_t)(wr[c] * inv);
}

// ---------------------------------------------------------------------------
// 2) x -> bf16 copy + per-token magnitude ||x||/sqrt(D)
// ---------------------------------------------------------------------------
__global__ __launch_bounds__(256) void prep_x_kernel(const float* __restrict__ x,
                                                     bf16_t* __restrict__ xb,
                                                     float* __restrict__ mag) {
    int tok = blockIdx.x;                 // 0..8191
    const float* xr = x + (size_t)tok * 768;
    float ss = 0.f;
    for (int c = threadIdx.x; c < 768; c += 256) { float v = xr[c]; ss += v * v; }
    for (int m = 32; m; m >>= 1) ss += __shfl_xor(ss, m, 64);
    __shared__ float red[4];
    if ((threadIdx.x & 63) == 0) red[threadIdx.x >> 6] = ss;
    __syncthreads();
    float tot = red[0] + red[1] + red[2] + red[3];
    if (threadIdx.x == 0) mag[tok] = sqrtf(tot) * 0.036084391824352f;  // 1/sqrt(768)
    bf16_t* xo = xb + (size_t)tok * 768;
    for (int c = threadIdx.x; c < 768; c += 256) xo[c] = (bf16_t)xr[c];
}

// ---------------------------------------------------------------------------
// 3) GEMM1: qkv = xb(8192x768) @ wn^T(2304x768) -> bf16 in (p,b,h,t,d) layout
//    tile 128x128, BK=32, 4 waves in 2x2. Fused q/k head-dim normalize:
//    each wave's 64-col range is exactly one head (wc in {0,64}); a given
//    output row-seg lives in one quad (16 lanes x 4 j-regs) -> shfl reduce.
// ---------------------------------------------------------------------------
__global__ __launch_bounds__(256) void gemm_qkv_kernel(const bf16_t* __restrict__ A,
                                                       const bf16_t* __restrict__ Bw,
                                                       bf16_t* __restrict__ qkvh) {
    __shared__ bf16_t As[128][40];   // +8 pad: 80B rows -> 2-way banks (free)
    __shared__ bf16_t Bs[128][40];
    const int m0 = blockIdx.x * 128;
    const int n0 = blockIdx.y * 128;
    const int tid = threadIdx.x;
    const int wave = tid >> 6, lane = tid & 63;
    const int quad = lane >> 4, l16 = lane & 15;
    const int wr = (wave >> 1) * 64, wc = (wave & 1) * 64;

    floatx4 acc[4][4];
    for (int i = 0; i < 4; i++)
        for (int j = 0; j < 4; j++) acc[i][j] = (floatx4){0.f, 0.f, 0.f, 0.f};

    for (int k0 = 0; k0 < 768; k0 += 32) {
        for (int s = tid; s < 512; s += 256) {
            int r = s >> 2, cs = (s & 3) * 8;
            *(uint4*)&As[r][cs] = *(const uint4*)&A[(size_t)(m0 + r) * 768 + k0 + cs];
            *(uint4*)&Bs[r][cs] = *(const uint4*)&Bw[(size_t)(n0 + r) * 768 + k0 + cs];
        }
        __syncthreads();
        bf16x8 af[4], bfr[4];
        for (int i = 0; i < 4; i++) af[i]  = *(const bf16x8*)&As[wr + i * 16 + l16][quad * 8];
        for (int j = 0; j < 4; j++) bfr[j] = *(const bf16x8*)&Bs[wc + j * 16 + l16][quad * 8];
        for (int i = 0; i < 4; i++)
            for (int j = 0; j < 4; j++) acc[i][j] = MFMA16x16x32(af[i], bfr[j], acc[i][j]);
        __syncthreads();
    }
    // epilogue: fused per-head normalize for q,k (p<2), then scatter to
    // qkvh[(((p*4+b)*12+h)*2048+t)*64+d], bf16
    const int nbase = n0 + wc;            // wave-uniform; spans one 64-wide head
    const int p = nbase / 768;
    const int rem0 = nbase - p * 768;
    const int h = rem0 >> 6;
    for (int i = 0; i < 4; i++)
        for (int r = 0; r < 4; r++) {
            float vals[4], ss = 0.f;
            for (int j = 0; j < 4; j++) { float v = acc[i][j][r]; vals[j] = v; ss += v * v; }
            ss += __shfl_xor(ss, 1, 64);
            ss += __shfl_xor(ss, 2, 64);
            ss += __shfl_xor(ss, 4, 64);
            ss += __shfl_xor(ss, 8, 64);
            float scale = (p < 2) ? 8.0f / (sqrtf(ss) + kEPS) : 1.0f;
            int m = m0 + wr + i * 16 + quad * 4 + r;
            int bat = m >> 11, t = m & 2047;
            bf16_t* dst = qkvh + ((((size_t)p * 4 + bat) * 12 + h) * 2048 + t) * 64;
            for (int j = 0; j < 4; j++) {
                int d = j * 16 + l16;
                dst[d] = (bf16_t)(vals[j] * scale);
            }
        }
}

// ---------------------------------------------------------------------------
// 5) transpose v part (p=2) to vT[(b*12+h)*64 + d][t], with pi-permuted
//    column order inside each 64-block: stored position s' holds V[pi_inv(s')].
//    pi(s) = (s&15)*4 + (s>>4);  pi_inv(s') = ((s'&3)<<4) + (s'>>2).
// ---------------------------------------------------------------------------
__global__ __launch_bounds__(256) void transpose_v_kernel(const bf16_t* __restrict__ qkvh,
                                                          bf16_t* __restrict__ vT) {
    int bh = blockIdx.x;           // 0..47
    int t0 = blockIdx.y * 64;      // 32 tiles
    __shared__ bf16_t tile[64][65];
    const bf16_t* src = qkvh + (((size_t)(2 * 4 * 12) + bh) * 2048 + t0) * 64;
    for (int s = threadIdx.x; s < 512; s += 256) {
        int r = s >> 3, cs = (s & 7) * 8;
        bf16_t tmp[8];
        *(uint4*)tmp = *(const uint4*)&src[(size_t)r * 64 + cs];
        for (int j = 0; j < 8; j++) tile[r][cs + j] = tmp[j];
    }
    __syncthreads();
    bf16_t* dst = vT + ((size_t)bh * 64) * 2048 + t0;
    for (int s = threadIdx.x; s < 512; s += 256) {
        int d = s >> 3, ts = (s & 7) * 8;
        bf16_t tmp[8];
        for (int j = 0; j < 8; j++) {
            int sp = ts + j;                       // permuted position
            int t_src = ((sp & 3) << 4) + (sp >> 2);
            tmp[j] = tile[t_src][d];
        }
        *(uint4*)&dst[(size_t)d * 2048 + ts] = *(uint4*)tmp;
    }
}

// ---------------------------------------------------------------------------
// 6) sigmoid attention, fused per-head output normalize + mag rescale.
//    grid (T/128, 48). Q-tile 128 rows, s-tile 64, dbuf K/V, 1 barrier/iter.
//    LDS 48KB -> 3 blocks/CU. XOR-swizzled layout (16B blk ^= row&7).
// ---------------------------------------------------------------------------
__global__ __launch_bounds__(256, 3) void attn_kernel(const bf16_t* __restrict__ qkvh,
                                                      const bf16_t* __restrict__ vT,
                                                      const float* __restrict__ mag,
                                                      bf16_t* __restrict__ y) {
    __shared__ bf16_t QP[128 * 64];          // Q tile, then reused as Ps
    __shared__ bf16_t KV[2][2][64 * 64];     // [buf][0=K,1=V(pi-order)]

    const int bh = blockIdx.y, bat = bh / 12, h = bh % 12;
    const int m0 = blockIdx.x * 128;
    const bf16_t* qbase = qkvh + (((size_t)bat * 12 + h) * 2048) * 64;            // p=0
    const bf16_t* kbase = qkvh + (((size_t)(4 + bat) * 12 + h) * 2048) * 64;      // p=1
    const bf16_t* vbase = vT + ((size_t)bh * 64) * 2048;

    const int tid = threadIdx.x, wave = tid >> 6, lane = tid & 63;
    const int quad = lane >> 4, l16 = lane & 15;

    // ---- stage Q (swizzled) ----
    for (int s = tid; s < 1024; s += 256) {
        int r = s >> 3, blk = s & 7;
        *(uint4*)&QP[r * 64 + ((blk ^ (r & 7)) * 8)] =
            *(const uint4*)&qbase[(size_t)(m0 + r) * 64 + blk * 8];
    }

    // ---- K/V prefetch registers (one s-tile ahead) ----
    uint4 kr0, kr1, vr0, vr1;
    const int sl0r = tid >> 3,          sl0b = tid & 7;
    const int sl1r = (tid + 256) >> 3,  sl1b = (tid + 256) & 7;   // = tid&7
    auto issue = [&](int s0) {
        kr0 = *(const uint4*)&kbase[(size_t)(s0 + sl0r) * 64 + sl0b * 8];
        kr1 = *(const uint4*)&kbase[(size_t)(s0 + sl1r) * 64 + sl1b * 8];
        vr0 = *(const uint4*)&vbase[(size_t)sl0r * 2048 + s0 + sl0b * 8];
        vr1 = *(const uint4*)&vbase[(size_t)sl1r * 2048 + s0 + sl1b * 8];
    };
    const int sw0 = ((sl0b ^ (sl0r & 7)) * 8);
    const int sw1 = ((sl1b ^ (sl1r & 7)) * 8);
    auto commit = [&](int buf) {
        *(uint4*)&KV[buf][0][sl0r * 64 + sw0] = kr0;
        *(uint4*)&KV[buf][0][sl1r * 64 + sw1] = kr1;
        *(uint4*)&KV[buf][1][sl0r * 64 + sw0] = vr0;
        *(uint4*)&KV[buf][1][sl1r * 64 + sw1] = vr1;
    };

    issue(0);
    __syncthreads();   // Q staged

    // ---- Q fragments -> registers (wave-private rows; QP freed for Ps) ----
    bf16x8 qf[2][2];
#pragma unroll
    for (int i = 0; i < 2; i++)
#pragma unroll
        for (int hh = 0; hh < 2; hh++) {
            int row = wave * 32 + i * 16 + l16;
            qf[i][hh] = *(const bf16x8*)&QP[row * 64 + (((hh * 4 + quad) ^ (l16 & 7)) * 8)];
        }

    commit(0);
    issue(64);
    __syncthreads();   // KV[0] visible (also covers Q-frag reads vs Ps writes x-wave: rows are wave-private anyway)

    floatx4 o[2][4];
#pragma unroll
    for (int i = 0; i < 2; i++)
#pragma unroll
        for (int j = 0; j < 4; j++) o[i][j] = (floatx4){0.f, 0.f, 0.f, 0.f};

    const float kC = -0.18033688011112042f;   // -0.125 * log2(e)

    for (int it = 0; it < 32; ++it) {
        const bf16_t* Ks = KV[it & 1][0];
        const bf16_t* Vt = KV[it & 1][1];
        if (it < 31) {
            commit((it + 1) & 1);        // regs loaded one iter ago
            if (it < 30) issue((it + 2) * 64);
        }

        // ---- S = Q.K^T (32 q-rows x 64 s per wave) ----
        floatx4 sacc[2][4];
#pragma unroll
        for (int i = 0; i < 2; i++)
#pragma unroll
            for (int j = 0; j < 4; j++) sacc[i][j] = (floatx4){0.f, 0.f, 0.f, 0.f};
#pragma unroll
        for (int j = 0; j < 4; j++) {
            int row = j * 16 + l16;
            bf16x8 b0 = *(const bf16x8*)&Ks[row * 64 + ((quad ^ (l16 & 7)) * 8)];
            bf16x8 b1 = *(const bf16x8*)&Ks[row * 64 + (((4 + quad) ^ (l16 & 7)) * 8)];
#pragma unroll
            for (int i = 0; i < 2; i++) {
                sacc[i][j] = MFMA16x16x32(qf[i][0], b0, sacc[i][j]);
                sacc[i][j] = MFMA16x16x32(qf[i][1], b1, sacc[i][j]);
            }
        }

        // ---- sigmoid -> Ps (pi-packed b64, wave-private rows of QP) ----
#pragma unroll
        for (int i = 0; i < 2; i++)
#pragma unroll
            for (int r = 0; r < 4; r++) {
                int row = wave * 32 + i * 16 + quad * 4 + r;
                bf16x4 pk;
#pragma unroll
                for (int j = 0; j < 4; j++) {
                    float t = __builtin_amdgcn_exp2f(sacc[i][j][r] * kC);
                    pk[j] = (bf16_t)__builtin_amdgcn_rcpf(1.0f + t);
                }
                // 8B granule swizzle: blk = l16>>1, half = l16&1
                *(bf16x4*)&QP[row * 64 + (((l16 >> 1) ^ (row & 7)) * 8) + (l16 & 1) * 4] = pk;
            }

        // ---- O += P.V (A from QP, B from Vt, both pi-order) ----
        bf16x8 af[2][2];
#pragma unroll
        for (int i = 0; i < 2; i++) {
            int row = wave * 32 + i * 16 + l16;
            af[i][0] = *(const bf16x8*)&QP[row * 64 + ((quad ^ (l16 & 7)) * 8)];
            af[i][1] = *(const bf16x8*)&QP[row * 64 + (((4 + quad) ^ (l16 & 7)) * 8)];
        }
#pragma unroll
        for (int j = 0; j < 4; j++) {
            int row = j * 16 + l16;
            bf16x8 b0 = *(const bf16x8*)&Vt[row * 64 + ((quad ^ (l16 & 7)) * 8)];
            bf16x8 b1 = *(const bf16x8*)&Vt[row * 64 + (((4 + quad) ^ (l16 & 7)) * 8)];
#pragma unroll
            for (int i = 0; i < 2; i++) {
                o[i][j] = MFMA16x16x32(af[i][0], b0, o[i][j]);
                o[i][j] = MFMA16x16x32(af[i][1], b1, o[i][j]);
            }
        }
        __syncthreads();   // one barrier per s-tile
    }

    // ---- epilogue: out = mag * 8 * (kGAIN/sqrt(T)) * o / (||...|| + eps) ----
    const float kfac = kGAIN * 0.02209708691207961f;  // 1.8402/sqrt(2048)
#pragma unroll
    for (int i = 0; i < 2; i++)
#pragma unroll
        for (int r = 0; r < 4; r++) {
            int t = m0 + wave * 32 + i * 16 + quad * 4 + r;
            float vals[4];
            float ss = 0.f;
#pragma unroll
            for (int j = 0; j < 4; j++) {
                float v = o[i][j][r] * kfac;
                vals[j] = v;
                ss += v * v;
            }
            for (int msk = 1; msk < 16; msk <<= 1) ss += __shfl_xor(ss, msk, 64);
            float mg = mag[bat * 2048 + t];
            float sc = mg * 8.0f / (sqrtf(ss) + kEPS);
#pragma unroll
            for (int j = 0; j < 4; j++) {
                int d = j * 16 + l16;
                y[((size_t)(bat * 2048 + t)) * 768 + h * 64 + d] = (bf16_t)(vals[j] * sc);
            }
        }
}

// ---------------------------------------------------------------------------
// 7) GEMM2: out = y(8192x768) @ ow^T(768x768) -> fp32 d_out
// ---------------------------------------------------------------------------
__global__ __launch_bounds__(256) void gemm_out_kernel(const bf16_t* __restrict__ A,
                                                       const bf16_t* __restrict__ Bw,
                                                       float* __restrict__ out) {
    __shared__ bf16_t As[128][40];
    __shared__ bf16_t Bs[128][40];
    const int m0 = blockIdx.x * 128;
    const int n0 = blockIdx.y * 128;
    const int tid = threadIdx.x;
    const int wave = tid >> 6, lane = tid & 63;
    const int quad = lane >> 4, l16 = lane & 15;
    const int wr = (wave >> 1) * 64, wc = (wave & 1) * 64;

    floatx4 acc[4][4];
    for (int i = 0; i < 4; i++)
        for (int j = 0; j < 4; j++) acc[i][j] = (floatx4){0.f, 0.f, 0.f, 0.f};

    for (int k0 = 0; k0 < 768; k0 += 32) {
        for (int s = tid; s < 512; s += 256) {
            int r = s >> 2, cs = (s & 3) * 8;
            *(uint4*)&As[r][cs] = *(const uint4*)&A[(size_t)(m0 + r) * 768 + k0 + cs];
            *(uint4*)&Bs[r][cs] = *(const uint4*)&Bw[(size_t)(n0 + r) * 768 + k0 + cs];
        }
        __syncthreads();
        bf16x8 af[4], bfr[4];
        for (int i = 0; i < 4; i++) af[i]  = *(const bf16x8*)&As[wr + i * 16 + l16][quad * 8];
        for (int j = 0; j < 4; j++) bfr[j] = *(const bf16x8*)&Bs[wc + j * 16 + l16][quad * 8];
        for (int i = 0; i < 4; i++)
            for (int j = 0; j < 4; j++) acc[i][j] = MFMA16x16x32(af[i], bfr[j], acc[i][j]);
        __syncthreads();
    }
    for (int i = 0; i < 4; i++)
        for (int j = 0; j < 4; j++) {
            int n = n0 + wc + j * 16 + l16;
            for (int r = 0; r < 4; r++) {
                int m = m0 + wr + i * 16 + quad * 4 + r;
                out[(size_t)m * 768 + n] = acc[i][j][r];
            }
        }
}

// ---------------------------------------------------------------------------
extern "C" void kernel_launch(void* const* d_in, const int* in_sizes, int n_in,
                              void* d_out, int out_size, void* d_ws, size_t ws_size,
                              hipStream_t stream) {
    const float* x     = (const float*)d_in[0];   // (4,2048,768)
    const float* qkv_w = (const float*)d_in[1];   // (2304,768)
    const float* out_w = (const float*)d_in[2];   // (768,768)
    float* out = (float*)d_out;

    char* ws = (char*)d_ws;
    bf16_t* wn   = (bf16_t*)(ws + 0);            //  3,538,944  (2304x768 bf16)
    bf16_t* ow   = (bf16_t*)(ws + 3538944);      //  1,179,648  (768x768 bf16)
    bf16_t* xb   = (bf16_t*)(ws + 4718592);      // 12,582,912  (8192x768 bf16)
    float*  mag  = (float*) (ws + 17301504);     //     32,768  (8192 fp32)
    bf16_t* qkvh = (bf16_t*)(ws + 17334272);     // 37,748,736  (3x4x12x2048x64 bf16)
    bf16_t* vT   = (bf16_t*)(ws + 55083008);     // 12,582,912  (48x64x2048 bf16)
    bf16_t* y    = (bf16_t*)(ws + 67665920);     // 12,582,912  (8192x768 bf16)
    // total 80,248,832 bytes

    rownorm_kernel<<<2304, 256, 0, stream>>>(qkv_w, wn, 768);
    rownorm_kernel<<<768, 256, 0, stream>>>(out_w, ow, 768);
    prep_x_kernel<<<8192, 256, 0, stream>>>(x, xb, mag);
    gemm_qkv_kernel<<<dim3(64, 18), 256, 0, stream>>>(xb, wn, qkvh);
    transpose_v_kernel<<<dim3(48, 32), 256, 0, stream>>>(qkvh, vT);
    attn_kernel<<<dim3(16, 48), 256, 0, stream>>>(qkvh, vT, mag, y);
    gemm_out_kernel<<<dim3(64, 6), 256, 0, stream>>>(y, ow, out);
}

// Round 3
// 252.620 us; speedup vs baseline: 1.4988x; 1.0028x over previous
//
#include <hip/hip_runtime.h>
#include <hip/hip_bf16.h>

// Attention_4363686773373: sigmoid attention block, all-bf16 MFMA pipeline.
// B=4 T=2048 D=768 H=12 HD=64.  Output fp32.
// R3: attn -> 512 thr / 8 waves x 16 q-rows (24 waves/CU @ 48KB LDS),
// sigmoid scale folded into q (gemm_qkv epilogue), XCD-affine grid (48,16),
// GEMMs BK=64 (half the barriers).

typedef __bf16 bf16_t;
typedef __bf16 bf16x8 __attribute__((ext_vector_type(8)));
typedef __bf16 bf16x4 __attribute__((ext_vector_type(4)));
typedef float floatx4 __attribute__((ext_vector_type(4)));

#define MFMA16x16x32(a, b, c) __builtin_amdgcn_mfma_f32_16x16x32_bf16((a), (b), (c), 0, 0, 0)

static constexpr float kEPS  = 1e-4f;
static constexpr float kGAIN = 1.8402f;
static constexpr float kC    = -0.18033688011112042f;   // -0.125 * log2(e)

// ---------------------------------------------------------------------------
// 1) row-normalize a (nrows x ncols) fp32 weight matrix -> bf16: w/(||w||+eps)
// ---------------------------------------------------------------------------
__global__ __launch_bounds__(256) void rownorm_kernel(const float* __restrict__ w,
                                                      bf16_t* __restrict__ wn,
                                                      int ncols) {
    int row = blockIdx.x;
    const float* wr = w + (size_t)row * ncols;
    float ss = 0.f;
    for (int c = threadIdx.x; c < ncols; c += 256) { float v = wr[c]; ss += v * v; }
    for (int m = 32; m; m >>= 1) ss += __shfl_xor(ss, m, 64);
    __shared__ float red[4];
    if ((threadIdx.x & 63) == 0) red[threadIdx.x >> 6] = ss;
    __syncthreads();
    float inv = 1.0f / (sqrtf(red[0] + red[1] + red[2] + red[3]) + kEPS);
    bf16_t* wo = wn + (size_t)row * ncols;
    for (int c = threadIdx.x; c < ncols; c += 256) wo[c] = (bf16_t)(wr[c] * inv);
}

// ---------------------------------------------------------------------------
// 2) x -> bf16 copy + per-token magnitude ||x||/sqrt(D)
// ---------------------------------------------------------------------------
__global__ __launch_bounds__(256) void prep_x_kernel(const float* __restrict__ x,
                                                     bf16_t* __restrict__ xb,
                                                     float* __restrict__ mag) {
    int tok = blockIdx.x;                 // 0..8191
    const float* xr = x + (size_t)tok * 768;
    float ss = 0.f;
    for (int c = threadIdx.x; c < 768; c += 256) { float v = xr[c]; ss += v * v; }
    for (int m = 32; m; m >>= 1) ss += __shfl_xor(ss, m, 64);
    __shared__ float red[4];
    if ((threadIdx.x & 63) == 0) red[threadIdx.x >> 6] = ss;
    __syncthreads();
    float tot = red[0] + red[1] + red[2] + red[3];
    if (threadIdx.x == 0) mag[tok] = sqrtf(tot) * 0.036084391824352f;  // 1/sqrt(768)
    bf16_t* xo = xb + (size_t)tok * 768;
    for (int c = threadIdx.x; c < 768; c += 256) xo[c] = (bf16_t)xr[c];
}

// ---------------------------------------------------------------------------
// 3) GEMM1: qkv = xb(8192x768) @ wn^T(2304x768) -> bf16 in (p,b,h,t,d) layout
//    tile 128x128, BK=64, 4 waves 2x2. Fused per-head q/k normalize; q is
//    additionally scaled by kC so attn's sigmoid needs no multiply.
// ---------------------------------------------------------------------------
__global__ __launch_bounds__(256) void gemm_qkv_kernel(const bf16_t* __restrict__ A,
                                                       const bf16_t* __restrict__ Bw,
                                                       bf16_t* __restrict__ qkvh) {
    __shared__ bf16_t As[128][72];   // 64+8 pad: rows shift 4 banks -> <=2-way
    __shared__ bf16_t Bs[128][72];
    const int m0 = blockIdx.x * 128;
    const int n0 = blockIdx.y * 128;
    const int tid = threadIdx.x;
    const int wave = tid >> 6, lane = tid & 63;
    const int quad = lane >> 4, l16 = lane & 15;
    const int wr = (wave >> 1) * 64, wc = (wave & 1) * 64;

    floatx4 acc[4][4];
    for (int i = 0; i < 4; i++)
        for (int j = 0; j < 4; j++) acc[i][j] = (floatx4){0.f, 0.f, 0.f, 0.f};

    for (int k0 = 0; k0 < 768; k0 += 64) {
        for (int s = tid; s < 1024; s += 256) {
            int r = s >> 3, cs = (s & 7) * 8;
            *(uint4*)&As[r][cs] = *(const uint4*)&A[(size_t)(m0 + r) * 768 + k0 + cs];
            *(uint4*)&Bs[r][cs] = *(const uint4*)&Bw[(size_t)(n0 + r) * 768 + k0 + cs];
        }
        __syncthreads();
        bf16x8 af[4][2], bfr[4][2];
        for (int i = 0; i < 4; i++) {
            af[i][0] = *(const bf16x8*)&As[wr + i * 16 + l16][quad * 8];
            af[i][1] = *(const bf16x8*)&As[wr + i * 16 + l16][32 + quad * 8];
        }
        for (int j = 0; j < 4; j++) {
            bfr[j][0] = *(const bf16x8*)&Bs[wc + j * 16 + l16][quad * 8];
            bfr[j][1] = *(const bf16x8*)&Bs[wc + j * 16 + l16][32 + quad * 8];
        }
        for (int i = 0; i < 4; i++)
            for (int j = 0; j < 4; j++) {
                acc[i][j] = MFMA16x16x32(af[i][0], bfr[j][0], acc[i][j]);
                acc[i][j] = MFMA16x16x32(af[i][1], bfr[j][1], acc[i][j]);
            }
        __syncthreads();
    }
    // epilogue: fused per-head normalize for q,k; q also gets kC folded in.
    const int nbase = n0 + wc;            // wave-uniform; spans one 64-wide head
    const int p = nbase / 768;
    const int rem0 = nbase - p * 768;
    const int h = rem0 >> 6;
    for (int i = 0; i < 4; i++)
        for (int r = 0; r < 4; r++) {
            float vals[4], ss = 0.f;
            for (int j = 0; j < 4; j++) { float v = acc[i][j][r]; vals[j] = v; ss += v * v; }
            ss += __shfl_xor(ss, 1, 64);
            ss += __shfl_xor(ss, 2, 64);
            ss += __shfl_xor(ss, 4, 64);
            ss += __shfl_xor(ss, 8, 64);
            float scale = (p == 0) ? kC * 8.0f / (sqrtf(ss) + kEPS)
                        : (p == 1) ? 8.0f / (sqrtf(ss) + kEPS)
                                   : 1.0f;
            int m = m0 + wr + i * 16 + quad * 4 + r;
            int bat = m >> 11, t = m & 2047;
            bf16_t* dst = qkvh + ((((size_t)p * 4 + bat) * 12 + h) * 2048 + t) * 64;
            for (int j = 0; j < 4; j++) {
                int d = j * 16 + l16;
                dst[d] = (bf16_t)(vals[j] * scale);
            }
        }
}

// ---------------------------------------------------------------------------
// 5) transpose v part (p=2) to vT[(b*12+h)*64 + d][t], pi-permuted columns:
//    stored position s' holds V[((s'&3)<<4) + (s'>>2)].
// ---------------------------------------------------------------------------
__global__ __launch_bounds__(256) void transpose_v_kernel(const bf16_t* __restrict__ qkvh,
                                                          bf16_t* __restrict__ vT) {
    int bh = blockIdx.x;           // 0..47
    int t0 = blockIdx.y * 64;      // 32 tiles
    __shared__ bf16_t tile[64][65];
    const bf16_t* src = qkvh + (((size_t)(2 * 4 * 12) + bh) * 2048 + t0) * 64;
    for (int s = threadIdx.x; s < 512; s += 256) {
        int r = s >> 3, cs = (s & 7) * 8;
        bf16_t tmp[8];
        *(uint4*)tmp = *(const uint4*)&src[(size_t)r * 64 + cs];
        for (int j = 0; j < 8; j++) tile[r][cs + j] = tmp[j];
    }
    __syncthreads();
    bf16_t* dst = vT + ((size_t)bh * 64) * 2048 + t0;
    for (int s = threadIdx.x; s < 512; s += 256) {
        int d = s >> 3, ts = (s & 7) * 8;
        bf16_t tmp[8];
        for (int j = 0; j < 8; j++) {
            int sp = ts + j;                       // permuted position
            int t_src = ((sp & 3) << 4) + (sp >> 2);
            tmp[j] = tile[t_src][d];
        }
        *(uint4*)&dst[(size_t)d * 2048 + ts] = *(uint4*)tmp;
    }
}

// ---------------------------------------------------------------------------
// 6) sigmoid attention, fused per-head output normalize + mag rescale.
//    grid (48, 16): x = head (XCD-affine: 48%8==0 keeps a head on one XCD),
//    y = q-tile. 512 threads = 8 waves x 16 q-rows. s-tile 64, dbuf K/V,
//    one barrier per s-tile. LDS 48KB -> 3 blocks/CU -> 24 waves/CU.
// ---------------------------------------------------------------------------
__global__ __launch_bounds__(512, 6) void attn_kernel(const bf16_t* __restrict__ qkvh,
                                                      const bf16_t* __restrict__ vT,
                                                      const float* __restrict__ mag,
                                                      bf16_t* __restrict__ y) {
    __shared__ bf16_t QP[128 * 64];          // Q tile, then reused as Ps
    __shared__ bf16_t KV[2][2][64 * 64];     // [buf][0=K,1=V(pi-order)]

    const int bh = blockIdx.x, bat = bh / 12, h = bh % 12;
    const int m0 = blockIdx.y * 128;
    const bf16_t* qbase = qkvh + (((size_t)bat * 12 + h) * 2048) * 64;            // p=0
    const bf16_t* kbase = qkvh + (((size_t)(4 + bat) * 12 + h) * 2048) * 64;      // p=1
    const bf16_t* vbase = vT + ((size_t)bh * 64) * 2048;

    const int tid = threadIdx.x, wave = tid >> 6, lane = tid & 63;
    const int quad = lane >> 4, l16 = lane & 15;

    // ---- stage Q (swizzled): 1024 uint4 over 512 threads ----
    for (int s = tid; s < 1024; s += 512) {
        int r = s >> 3, blk = s & 7;
        *(uint4*)&QP[r * 64 + ((blk ^ (r & 7)) * 8)] =
            *(const uint4*)&qbase[(size_t)(m0 + r) * 64 + blk * 8];
    }

    // ---- K/V prefetch (1 uint4 of each per thread) ----
    uint4 kr, vr;
    const int slr = tid >> 3, slb = tid & 7;
    auto issue = [&](int s0) {
        kr = *(const uint4*)&kbase[(size_t)(s0 + slr) * 64 + slb * 8];
        vr = *(const uint4*)&vbase[(size_t)slr * 2048 + s0 + slb * 8];
    };
    const int sw = ((slb ^ (slr & 7)) * 8);
    auto commit = [&](int buf) {
        *(uint4*)&KV[buf][0][slr * 64 + sw] = kr;
        *(uint4*)&KV[buf][1][slr * 64 + sw] = vr;
    };

    issue(0);
    __syncthreads();   // Q staged

    // ---- Q fragments -> registers (wave-private rows; QP freed for Ps) ----
    const int qrow = wave * 16 + l16;
    bf16x8 qf0 = *(const bf16x8*)&QP[qrow * 64 + ((quad ^ (l16 & 7)) * 8)];
    bf16x8 qf1 = *(const bf16x8*)&QP[qrow * 64 + (((4 + quad) ^ (l16 & 7)) * 8)];

    commit(0);
    issue(64);
    __syncthreads();   // KV[0] visible; all qf reads done before Ps writes

    floatx4 o[4];
#pragma unroll
    for (int j = 0; j < 4; j++) o[j] = (floatx4){0.f, 0.f, 0.f, 0.f};

    for (int it = 0; it < 32; ++it) {
        const bf16_t* Ks = KV[it & 1][0];
        const bf16_t* Vt = KV[it & 1][1];
        if (it < 31) {
            commit((it + 1) & 1);        // regs loaded one iter ago
            if (it < 30) issue((it + 2) * 64);
        }

        // ---- S = Q.K^T (16 q-rows x 64 s per wave) ----
        floatx4 sacc[4];
#pragma unroll
        for (int j = 0; j < 4; j++) sacc[j] = (floatx4){0.f, 0.f, 0.f, 0.f};
#pragma unroll
        for (int j = 0; j < 4; j++) {
            int row = j * 16 + l16;
            bf16x8 b0 = *(const bf16x8*)&Ks[row * 64 + ((quad ^ (l16 & 7)) * 8)];
            bf16x8 b1 = *(const bf16x8*)&Ks[row * 64 + (((4 + quad) ^ (l16 & 7)) * 8)];
            sacc[j] = MFMA16x16x32(qf0, b0, sacc[j]);
            sacc[j] = MFMA16x16x32(qf1, b1, sacc[j]);
        }

        // ---- sigmoid = rcp(1+exp2(S)) (kC pre-folded into q) -> Ps ----
#pragma unroll
        for (int r = 0; r < 4; r++) {
            int row = wave * 16 + quad * 4 + r;
            bf16x4 pk;
#pragma unroll
            for (int j = 0; j < 4; j++) {
                float t = __builtin_amdgcn_exp2f(sacc[j][r]);
                pk[j] = (bf16_t)__builtin_amdgcn_rcpf(1.0f + t);
            }
            *(bf16x4*)&QP[row * 64 + (((l16 >> 1) ^ (row & 7)) * 8) + (l16 & 1) * 4] = pk;
        }

        // ---- O += P.V (A from QP, B from Vt, both pi-order) ----
        const int prow = wave * 16 + l16;
        bf16x8 af0 = *(const bf16x8*)&QP[prow * 64 + ((quad ^ (l16 & 7)) * 8)];
        bf16x8 af1 = *(const bf16x8*)&QP[prow * 64 + (((4 + quad) ^ (l16 & 7)) * 8)];
#pragma unroll
        for (int j = 0; j < 4; j++) {
            int row = j * 16 + l16;
            bf16x8 b0 = *(const bf16x8*)&Vt[row * 64 + ((quad ^ (l16 & 7)) * 8)];
            bf16x8 b1 = *(const bf16x8*)&Vt[row * 64 + (((4 + quad) ^ (l16 & 7)) * 8)];
            o[j] = MFMA16x16x32(af0, b0, o[j]);
            o[j] = MFMA16x16x32(af1, b1, o[j]);
        }
        __syncthreads();   // one barrier per s-tile
    }

    // ---- epilogue: out = mag * 8 * (kGAIN/sqrt(T)) * o / (||...|| + eps) ----
    const float kfac = kGAIN * 0.02209708691207961f;  // 1.8402/sqrt(2048)
#pragma unroll
    for (int r = 0; r < 4; r++) {
        int t = m0 + wave * 16 + quad * 4 + r;
        float vals[4];
        float ss = 0.f;
#pragma unroll
        for (int j = 0; j < 4; j++) {
            float v = o[j][r] * kfac;
            vals[j] = v;
            ss += v * v;
        }
        for (int msk = 1; msk < 16; msk <<= 1) ss += __shfl_xor(ss, msk, 64);
        float mg = mag[bat * 2048 + t];
        float sc = mg * 8.0f / (sqrtf(ss) + kEPS);
#pragma unroll
        for (int j = 0; j < 4; j++) {
            int d = j * 16 + l16;
            y[((size_t)(bat * 2048 + t)) * 768 + h * 64 + d] = (bf16_t)(vals[j] * sc);
        }
    }
}

// ---------------------------------------------------------------------------
// 7) GEMM2: out = y(8192x768) @ ow^T(768x768) -> fp32 d_out, BK=64
// ---------------------------------------------------------------------------
__global__ __launch_bounds__(256) void gemm_out_kernel(const bf16_t* __restrict__ A,
                                                       const bf16_t* __restrict__ Bw,
                                                       float* __restrict__ out) {
    __shared__ bf16_t As[128][72];
    __shared__ bf16_t Bs[128][72];
    const int m0 = blockIdx.x * 128;
    const int n0 = blockIdx.y * 128;
    const int tid = threadIdx.x;
    const int wave = tid >> 6, lane = tid & 63;
    const int quad = lane >> 4, l16 = lane & 15;
    const int wr = (wave >> 1) * 64, wc = (wave & 1) * 64;

    floatx4 acc[4][4];
    for (int i = 0; i < 4; i++)
        for (int j = 0; j < 4; j++) acc[i][j] = (floatx4){0.f, 0.f, 0.f, 0.f};

    for (int k0 = 0; k0 < 768; k0 += 64) {
        for (int s = tid; s < 1024; s += 256) {
            int r = s >> 3, cs = (s & 7) * 8;
            *(uint4*)&As[r][cs] = *(const uint4*)&A[(size_t)(m0 + r) * 768 + k0 + cs];
            *(uint4*)&Bs[r][cs] = *(const uint4*)&Bw[(size_t)(n0 + r) * 768 + k0 + cs];
        }
        __syncthreads();
        bf16x8 af[4][2], bfr[4][2];
        for (int i = 0; i < 4; i++) {
            af[i][0] = *(const bf16x8*)&As[wr + i * 16 + l16][quad * 8];
            af[i][1] = *(const bf16x8*)&As[wr + i * 16 + l16][32 + quad * 8];
        }
        for (int j = 0; j < 4; j++) {
            bfr[j][0] = *(const bf16x8*)&Bs[wc + j * 16 + l16][quad * 8];
            bfr[j][1] = *(const bf16x8*)&Bs[wc + j * 16 + l16][32 + quad * 8];
        }
        for (int i = 0; i < 4; i++)
            for (int j = 0; j < 4; j++) {
                acc[i][j] = MFMA16x16x32(af[i][0], bfr[j][0], acc[i][j]);
                acc[i][j] = MFMA16x16x32(af[i][1], bfr[j][1], acc[i][j]);
            }
        __syncthreads();
    }
    for (int i = 0; i < 4; i++)
        for (int j = 0; j < 4; j++) {
            int n = n0 + wc + j * 16 + l16;
            for (int r = 0; r < 4; r++) {
                int m = m0 + wr + i * 16 + quad * 4 + r;
                out[(size_t)m * 768 + n] = acc[i][j][r];
            }
        }
}

// ---------------------------------------------------------------------------
extern "C" void kernel_launch(void* const* d_in, const int* in_sizes, int n_in,
                              void* d_out, int out_size, void* d_ws, size_t ws_size,
                              hipStream_t stream) {
    const float* x     = (const float*)d_in[0];   // (4,2048,768)
    const float* qkv_w = (const float*)d_in[1];   // (2304,768)
    const float* out_w = (const float*)d_in[2];   // (768,768)
    float* out = (float*)d_out;

    char* ws = (char*)d_ws;
    bf16_t* wn   = (bf16_t*)(ws + 0);            //  3,538,944  (2304x768 bf16)
    bf16_t* ow   = (bf16_t*)(ws + 3538944);      //  1,179,648  (768x768 bf16)
    bf16_t* xb   = (bf16_t*)(ws + 4718592);      // 12,582,912  (8192x768 bf16)
    float*  mag  = (float*) (ws + 17301504);     //     32,768  (8192 fp32)
    bf16_t* qkvh = (bf16_t*)(ws + 17334272);     // 37,748,736  (3x4x12x2048x64 bf16)
    bf16_t* vT   = (bf16_t*)(ws + 55083008);     // 12,582,912  (48x64x2048 bf16)
    bf16_t* y    = (bf16_t*)(ws + 67665920);     // 12,582,912  (8192x768 bf16)
    // total 80,248,832 bytes

    rownorm_kernel<<<2304, 256, 0, stream>>>(qkv_w, wn, 768);
    rownorm_kernel<<<768, 256, 0, stream>>>(out_w, ow, 768);
    prep_x_kernel<<<8192, 256, 0, stream>>>(x, xb, mag);
    gemm_qkv_kernel<<<dim3(64, 18), 256, 0, stream>>>(xb, wn, qkvh);
    transpose_v_kernel<<<dim3(48, 32), 256, 0, stream>>>(qkvh, vT);
    attn_kernel<<<dim3(48, 16), 512, 0, stream>>>(qkvh, vT, mag, y);
    gemm_out_kernel<<<dim3(64, 6), 256, 0, stream>>>(y, ow, out);
}